// Round 2
// baseline (454.838 us; speedup 1.0000x reference)
//
#include <hip/hip_runtime.h>
#include <hip/hip_bf16.h>

// CP-decomposition eval: out[c][n] = lerp0[c] * lerp1[c] * lerp2[c]
// Tables (48x300 fp32 per axis) staged in LDS; C split into 3 groups of 16
// (57.6 KB LDS/block -> 2 blocks/CU). One thread per point per c-group.
// Store stream (384 MB) on VMEM overlaps the gather stream on the DS pipe.

#define NCOMP   48
#define CSUB    16          // comps per block (c-group)
#define NGROUP  (NCOMP / CSUB)
#define GSZ     300
#define BLOCK   512
#define GRID_X  512

__global__ __launch_bounds__(BLOCK, 4)
void cp_kernel(const float* __restrict__ xyz,
               const float* __restrict__ p0,
               const float* __restrict__ p1,
               const float* __restrict__ p2,
               float* __restrict__ out,
               int N)
{
    __shared__ float lds[3 * CSUB * GSZ];   // [axis][cLocal][g]

    const int cg = blockIdx.y;
    const int slice = CSUB * GSZ;           // 4800 floats, contiguous in global
    // Stage this block's component slice of each axis table (coalesced).
    for (int i = threadIdx.x; i < slice; i += BLOCK)
        lds[i]             = p0[cg * slice + i];
    for (int i = threadIdx.x; i < slice; i += BLOCK)
        lds[slice + i]     = p1[cg * slice + i];
    for (int i = threadIdx.x; i < slice; i += BLOCK)
        lds[2 * slice + i] = p2[cg * slice + i];
    __syncthreads();

    const int n0     = blockIdx.x * BLOCK + threadIdx.x;
    const int stride = GRID_X * BLOCK;

    for (int n = n0; n < N; n += stride) {
        const float x = xyz[3 * n + 0];
        const float y = xyz[3 * n + 1];
        const float z = xyz[3 * n + 2];

        // pos = ((coord + 1) * 0.5) * (G-1), matching reference eval order
        const float pos0 = (x + 1.0f) * 0.5f * (float)(GSZ - 1);
        const float pos1 = (y + 1.0f) * 0.5f * (float)(GSZ - 1);
        const float pos2 = (z + 1.0f) * 0.5f * (float)(GSZ - 1);

        // i0 = clamp(floor(pos),0,G-1); i1 = min(i0+1,G-1); w = pos - i0
        // equivalent: ic = min(i0, G-2); w' = pos - ic  (w'==1 at the top edge)
        int ic0 = min((int)pos0, GSZ - 2);
        int ic1 = min((int)pos1, GSZ - 2);
        int ic2 = min((int)pos2, GSZ - 2);
        const float w0 = pos0 - (float)ic0, om0 = 1.0f - w0;
        const float w1 = pos1 - (float)ic1, om1 = 1.0f - w1;
        const float w2 = pos2 - (float)ic2, om2 = 1.0f - w2;

        const float* __restrict__ b0 = &lds[ic0];
        const float* __restrict__ b1 = &lds[slice + ic1];
        const float* __restrict__ b2 = &lds[2 * slice + ic2];

        float* o = out + (size_t)cg * CSUB * (size_t)N + n;

        #pragma unroll
        for (int c = 0; c < CSUB; ++c) {
            const float* r0 = b0 + c * GSZ;   // pair {r0[0], r0[1]} -> ds_read2_b32
            const float* r1 = b1 + c * GSZ;
            const float* r2 = b2 + c * GSZ;
            const float u0 = r0[0] * om0 + r0[1] * w0;
            const float u1 = r1[0] * om1 + r1[1] * w1;
            const float u2 = r2[0] * om2 + r2[1] * w2;
            __builtin_nontemporal_store(u0 * u1 * u2, o);
            o += N;
        }
    }
}

extern "C" void kernel_launch(void* const* d_in, const int* in_sizes, int n_in,
                              void* d_out, int out_size, void* d_ws, size_t ws_size,
                              hipStream_t stream)
{
    const float* xyz = (const float*)d_in[0];
    const float* p0  = (const float*)d_in[1];
    const float* p1  = (const float*)d_in[2];
    const float* p2  = (const float*)d_in[3];
    float* out = (float*)d_out;
    const int N = in_sizes[0] / 3;

    dim3 grid(GRID_X, NGROUP, 1);
    dim3 block(BLOCK, 1, 1);
    cp_kernel<<<grid, block, 0, stream>>>(xyz, p0, p1, p2, out, N);
}